// Round 20
// baseline (72.301 us; speedup 1.0000x reference)
//
#include <hip/hip_runtime.h>
#include <hip/hip_fp16.h>

#define N_NODES 50000
#define N_EDGES 800000
#define IN_DIM 128
#define OUT_DIM 64
#define NEG_SLOPE 0.01f

#define BUCK_SHIFT 6
#define BUCK_NODES 64
#define NBUCK ((N_NODES + BUCK_NODES - 1) / BUCK_NODES)  // 782 (fits 10 bits)
#define CAP 1536          // fixed region per bucket; mean 1023, sigma 32
#define EPB 3136          // edges per binscat block
#define NBLK_SCAT ((N_EDGES + EPB - 1) / EPB)            // 256
#define NBLK_FC   ((N_NODES * 4 + 1023) / 1024)          // 196
#define NBLK_PREP (NBLK_SCAT + NBLK_FC)                  // 452 (<= 512 co-resident)

typedef unsigned int uint;

__device__ __forceinline__ uint f2h(float x) {
    return (uint)__half_as_ushort(__float2half_rn(x));
}
__device__ __forceinline__ float h2f(unsigned short u) {
    return __half2float(__ushort_as_half(u));
}

// K1 "prep": heterogeneous blocks. Blocks [0, NBLK_SCAT): binned edge scatter
// (independent of fc: payload = c*embed only; a_src deferred to gather; c
// computed locally). Blocks [NBLK_SCAT, NBLK_PREP): fc matmul -> z16, a_src,
// a_dst. The two block types have complementary bottlenecks (memory-latency vs
// VALU/LDS) and overlap on the CUs. gcursor pre-zeroed via hipMemsetAsync.
__launch_bounds__(1024)
__global__ void k_prep(const float* __restrict__ h,
                       const float* __restrict__ W_fc,
                       const float* __restrict__ W_attn,
                       const float* __restrict__ W_feat,
                       const int* __restrict__ src, const int* __restrict__ dst,
                       const float* __restrict__ embed,
                       uint* __restrict__ z16, float* __restrict__ a_src, float* __restrict__ a_dst,
                       int* __restrict__ gcursor, uint2* __restrict__ entries) {
    __shared__ float Wlds[IN_DIM * OUT_DIM];  // 32 KB (fc branch)
    __shared__ int hist[NBUCK];
    __shared__ int boff[NBUCK];
    __shared__ float s_c;

    int t = threadIdx.x;

    if (blockIdx.x < NBLK_SCAT) {
        // ---------------- binscat branch ----------------
        if (t < 64) {
            float p = W_feat[t] * W_attn[128 + t];
            #pragma unroll
            for (int off = 32; off; off >>= 1) p += __shfl_xor(p, off, 64);
            if (t == 0) s_c = p;
        }
        if (t < NBUCK) hist[t] = 0;
        __syncthreads();
        float cc = s_c;

        int e0 = blockIdx.x * EPB;
        int e1 = e0 + EPB; if (e1 > N_EDGES) e1 = N_EDGES;
        int m = e1 - e0;

        uint keyr[4]; float valr[4];
        bool own[4] = {false, false, false, false};

        int i0 = t * 4;
        if (i0 + 3 < m) {
            int4   s4 = ((const int4*)(src + e0))[t];
            int4   d4 = ((const int4*)(dst + e0))[t];
            float4 m4 = ((const float4*)(embed + e0))[t];
            int    ss[4] = {s4.x, s4.y, s4.z, s4.w};
            int    dd[4] = {d4.x, d4.y, d4.z, d4.w};
            float  mm[4] = {m4.x, m4.y, m4.z, m4.w};
            #pragma unroll
            for (int u = 0; u < 4; ++u) {
                uint b = (uint)dd[u] >> BUCK_SHIFT, dl = (uint)dd[u] & (BUCK_NODES - 1);
                keyr[u] = (uint)ss[u] | (dl << 16) | (b << 22);
                valr[u] = cc * mm[u];          // a_src[s] deferred to gather
                own[u] = true;
                atomicAdd(&hist[b], 1);
            }
        } else {
            #pragma unroll
            for (int u = 0; u < 4; ++u) {
                int i = i0 + u;
                if (i < m) {
                    int e = e0 + i;
                    int s = src[e], d = dst[e];
                    uint b = (uint)d >> BUCK_SHIFT, dl = (uint)d & (BUCK_NODES - 1);
                    keyr[u] = (uint)s | (dl << 16) | (b << 22);
                    valr[u] = cc * embed[e];
                    own[u] = true;
                    atomicAdd(&hist[b], 1);
                }
            }
        }
        __syncthreads();

        // reserve dense per-bucket ranges (gcursor counts RELATIVE offsets, pre-zeroed)
        if (t < NBUCK) {
            int c = hist[t];
            boff[t] = c ? atomicAdd(&gcursor[t], c) : 0;
            hist[t] = 0;
        }
        __syncthreads();

        // registers -> dense global write (line-dense per bucket-chunk)
        #pragma unroll
        for (int u = 0; u < 4; ++u) {
            if (!own[u]) continue;
            uint b = keyr[u] >> 22;
            int pos = (int)(b * CAP) + boff[b] + atomicAdd(&hist[b], 1);
            entries[pos] = make_uint2(keyr[u] & 0x3FFFFFu, __float_as_uint(valr[u]));
        }
    } else {
        // ---------------- fc branch ----------------
        const float4* Wg = (const float4*)W_fc;
        float4* Wl = (float4*)Wlds;
        #pragma unroll
        for (int i = 0; i < 2; ++i) Wl[t + i * 1024] = Wg[t + i * 1024];
        __syncthreads();

        int g = (blockIdx.x - NBLK_SCAT) * 1024 + t;
        int quad = g >> 4;        // nodes quad*4 .. quad*4+3
        int og   = g & 15;        // dims og*4 .. og*4+3
        int n0 = quad * 4;
        if (n0 >= N_NODES) return;

        bool valid[4];
        const float4* hrow[4];
        #pragma unroll
        for (int i = 0; i < 4; ++i) {
            int n = n0 + i;
            valid[i] = (n < N_NODES);
            hrow[i] = (const float4*)(h + (size_t)(valid[i] ? n : (N_NODES - 1)) * IN_DIM);
        }

        float acc[4][4];
        #pragma unroll
        for (int i = 0; i < 4; ++i)
            #pragma unroll
            for (int d = 0; d < 4; ++d) acc[i][d] = 0.f;

        for (int kc = 0; kc < IN_DIM / 4; ++kc) {
            float4 hv[4];
            #pragma unroll
            for (int i = 0; i < 4; ++i) hv[i] = hrow[i][kc];
            #pragma unroll
            for (int j = 0; j < 4; ++j) {
                float4 wv = *(const float4*)(Wlds + (size_t)(kc * 4 + j) * OUT_DIM + og * 4);
                #pragma unroll
                for (int i = 0; i < 4; ++i) {
                    float hh = (j == 0) ? hv[i].x : (j == 1) ? hv[i].y : (j == 2) ? hv[i].z : hv[i].w;
                    acc[i][0] += hh * wv.x;
                    acc[i][1] += hh * wv.y;
                    acc[i][2] += hh * wv.z;
                    acc[i][3] += hh * wv.w;
                }
            }
        }

        #pragma unroll
        for (int i = 0; i < 4; ++i) {
            if (!valid[i]) continue;
            uint* zr = z16 + (size_t)(n0 + i) * (OUT_DIM / 2) + og * 2;
            zr[0] = f2h(acc[i][0]) | (f2h(acc[i][1]) << 16);
            zr[1] = f2h(acc[i][2]) | (f2h(acc[i][3]) << 16);
        }

        float was0 = W_attn[og * 4], was1 = W_attn[og * 4 + 1],
              was2 = W_attn[og * 4 + 2], was3 = W_attn[og * 4 + 3];
        float wad0 = W_attn[64 + og * 4], wad1 = W_attn[64 + og * 4 + 1],
              wad2 = W_attn[64 + og * 4 + 2], wad3 = W_attn[64 + og * 4 + 3];
        #pragma unroll
        for (int i = 0; i < 4; ++i) {
            float ps = acc[i][0] * was0 + acc[i][1] * was1 + acc[i][2] * was2 + acc[i][3] * was3;
            float pd = acc[i][0] * wad0 + acc[i][1] * wad1 + acc[i][2] * wad2 + acc[i][3] * wad3;
            ps += __shfl_xor(ps, 1, 64); ps += __shfl_xor(ps, 2, 64);
            ps += __shfl_xor(ps, 4, 64); ps += __shfl_xor(ps, 8, 64);
            pd += __shfl_xor(pd, 1, 64); pd += __shfl_xor(pd, 2, 64);
            pd += __shfl_xor(pd, 4, 64); pd += __shfl_xor(pd, 8, 64);
            if (og == 0 && valid[i]) { a_src[n0 + i] = ps; a_dst[n0 + i] = pd; }
        }
    }
}

// K2: gather, one block (1024 threads) per 64-node bucket. Phase A: read
// entries, fold in a_src[s] (random L2 gather, latency-hidden), stash + hist.
// Wave 0 scans 64 counters. Phase C: ev = partial + a_dst_lds[dl], leaky, exp
// -> counting-sort into packed 4B (src | f16(ex)<<16). Phase D: owner-compute,
// wave wid handles nodes [wid*4, wid*4+4); ceil(c/8) masked 8-slot iterations.
__launch_bounds__(1024)
__global__ void k_gather(const int* __restrict__ gcursor, const uint2* __restrict__ entries,
                         const float* __restrict__ a_src, const float* __restrict__ a_dst,
                         const uint* __restrict__ z16, float* __restrict__ out) {
    __shared__ uint2 s_stash[CAP];                    // 12 KB
    __shared__ uint  s_pk2[CAP];                      // 6 KB
    __shared__ float s_adst[BUCK_NODES];
    __shared__ int hist[BUCK_NODES], hoff[BUCK_NODES], hcur[BUCK_NODES];

    int b = blockIdx.x;
    int t = threadIdx.x, lane = t & 63, wid = t >> 6;
    int base = b * CAP;
    int m = gcursor[b];             // bucket edge count (relative cursor)
    if (m > CAP) m = CAP;           // safety clamp

    if (t < BUCK_NODES) {
        hist[t] = 0;
        int n = b * BUCK_NODES + t;
        s_adst[t] = (n < N_NODES) ? a_dst[n] : 0.f;
    }
    __syncthreads();

    // phase A: global read -> fold a_src -> stash + histogram
    for (int i = t; i < m; i += 1024) {
        uint2 p = entries[base + i];
        p.y = __float_as_uint(__uint_as_float(p.y) + a_src[p.x & 0xFFFFu]);
        s_stash[i] = p;
        atomicAdd(&hist[(p.x >> 16) & 63], 1);
    }
    __syncthreads();

    if (wid == 0) {  // wave 0: exclusive scan of 64 counters
        int v = hist[lane], sc = v;
        #pragma unroll
        for (int off = 1; off < 64; off <<= 1) {
            int u = __shfl_up(sc, off, 64);
            if (lane >= off) sc += u;
        }
        hoff[lane] = sc - v;
        hcur[lane] = sc - v;
    }
    __syncthreads();

    // phase C: finish e (leaky+exp) and counting-sort into packed 4B
    for (int i = t; i < m; i += 1024) {
        uint2 p = s_stash[i];
        int dl = (p.x >> 16) & 63;
        float ev = __uint_as_float(p.y) + s_adst[dl];
        ev = (ev >= 0.f) ? ev : NEG_SLOPE * ev;
        float ex = __expf(ev);  // segment-max skipped: softmax shift-invariant, e is O(5)
        int pos = atomicAdd(&hcur[dl], 1);
        s_pk2[pos] = (p.x & 0xFFFFu) | (f2h(ex) << 16);
    }
    __syncthreads();

    // phase D: owner-compute with masked 8-slot iterations
    int half = lane >> 5, dp = lane & 31;
    for (int k = 0; k < 4; ++k) {
        int dl = wid * 4 + k;
        int n = b * BUCK_NODES + dl;
        if (n >= N_NODES) continue;
        int j0 = hoff[dl], c = hist[dl], j1 = j0 + c;
        float accx = 0.f, accy = 0.f, den = 0.f;
        for (int j = j0; j < j1; j += 8) {
            uint pk[4];
            #pragma unroll
            for (int u = 0; u < 4; ++u) {
                int idx = j + 4 * half + u;
                int idc = (idx < j1) ? idx : (j1 - 1);
                pk[u] = s_pk2[idc];
                if (idx >= j1) pk[u] &= 0xFFFFu;   // zero f16 ex -> no-op edge
            }
            uint zv[4];
            #pragma unroll
            for (int u = 0; u < 4; ++u) zv[u] = z16[(size_t)(pk[u] & 0xFFFFu) * 32 + dp];
            #pragma unroll
            for (int u = 0; u < 4; ++u) {
                float ex = h2f((unsigned short)(pk[u] >> 16));
                den  += ex;
                accx += ex * h2f((unsigned short)(zv[u] & 0xFFFFu));
                accy += ex * h2f((unsigned short)(zv[u] >> 16));
            }
        }
        accx += __shfl_xor(accx, 32, 64);
        accy += __shfl_xor(accy, 32, 64);
        den  += __shfl_xor(den, 32, 64);
        if (lane < 32) {
            float2 r = (c > 0) ? make_float2(accx / den, accy / den) : make_float2(0.f, 0.f);
            ((float2*)(out + (size_t)n * OUT_DIM))[dp] = r;
        }
    }
}

extern "C" void kernel_launch(void* const* d_in, const int* in_sizes, int n_in,
                              void* d_out, int out_size, void* d_ws, size_t ws_size,
                              hipStream_t stream) {
    const float* h      = (const float*)d_in[0];
    const float* embed  = (const float*)d_in[1];
    const int*   src    = (const int*)d_in[2];
    const int*   dst    = (const int*)d_in[3];
    const float* W_fc   = (const float*)d_in[4];
    const float* W_attn = (const float*)d_in[5];
    const float* W_feat = (const float*)d_in[6];

    float* ws      = (float*)d_ws;
    uint*  z16     = (uint*)ws;                         // N*32 uints (6.4MB)
    uint2* entries = (uint2*)(z16 + (size_t)N_NODES * 32);  // NBUCK*CAP uint2 (9.6MB)
    float* a_src   = (float*)(entries + (size_t)NBUCK * CAP);  // N f32
    float* a_dst   = a_src + N_NODES;                   // N f32
    int*   gcursor = (int*)(a_dst + N_NODES);           // NBUCK int (relative counts)

    float* out = (float*)d_out;

    hipMemsetAsync(gcursor, 0, NBUCK * sizeof(int), stream);
    k_prep<<<NBLK_PREP, 1024, 0, stream>>>(h, W_fc, W_attn, W_feat, src, dst, embed,
                                           z16, a_src, a_dst, gcursor, entries);
    k_gather<<<NBUCK, 1024, 0, stream>>>(gcursor, entries, a_src, a_dst, z16, out);
}

// Round 21
// 68.853 us; speedup vs baseline: 1.0501x; 1.0501x over previous
//
#include <hip/hip_runtime.h>
#include <hip/hip_fp16.h>

#define N_NODES 50000
#define N_EDGES 800000
#define IN_DIM 128
#define OUT_DIM 64
#define NEG_SLOPE 0.01f

#define BUCK_SHIFT 6
#define BUCK_NODES 64
#define NBUCK ((N_NODES + BUCK_NODES - 1) / BUCK_NODES)  // 782 (< 1024 -> fits 10 bits)
#define CAP 1536          // fixed region per bucket; mean 1023, sigma 32 -> 16-sigma headroom
#define EPB 3136          // edges per binscat block (256 blocks -> every CU active)
#define NBLK_SCAT ((N_EDGES + EPB - 1) / EPB)            // 256

typedef unsigned int uint;

__device__ __forceinline__ uint f2h(float x) {
    return (uint)__half_as_ushort(__float2half_rn(x));
}
__device__ __forceinline__ float h2f(unsigned short u) {
    return __half2float(__ushort_as_half(u));
}

// K1: z = h @ W_fc -> f16-packed z16; a_src = z.Wa_src, a_dst = z.Wa_dst.
// Register-blocked 4 nodes x 4 dims per thread (LDS reads amortized 4x).
// Fused: init gcursor; block 0 computes c = W_feat.Wa_feat.
__launch_bounds__(256)
__global__ void k_fc(const float* __restrict__ h,
                     const float* __restrict__ W_fc,
                     const float* __restrict__ W_attn,
                     const float* __restrict__ W_feat,
                     uint* __restrict__ z16, float* __restrict__ a_src, float* __restrict__ a_dst,
                     int* __restrict__ gcursor, float* __restrict__ c_ws) {
    __shared__ float Wlds[IN_DIM * OUT_DIM];  // 32 KB, [k][out] row-major
    const float4* Wg = (const float4*)W_fc;
    float4* Wl = (float4*)Wlds;
    #pragma unroll
    for (int i = 0; i < 8; ++i) Wl[threadIdx.x + i * 256] = Wg[threadIdx.x + i * 256];

    int g = blockIdx.x * 256 + threadIdx.x;
    if (g < NBUCK) gcursor[g] = g * CAP;
    if (blockIdx.x == 0 && threadIdx.x < 64) {
        int lane = threadIdx.x;
        float p = W_feat[lane] * W_attn[128 + lane];
        #pragma unroll
        for (int off = 32; off; off >>= 1) p += __shfl_xor(p, off, 64);
        if (lane == 0) c_ws[0] = p;
    }
    __syncthreads();

    int quad = g >> 4;        // node group: nodes quad*4 .. quad*4+3
    int og   = g & 15;        // output group: dims og*4 .. og*4+3
    int n0 = quad * 4;
    if (n0 >= N_NODES) return;

    bool valid[4];
    const float4* hrow[4];
    #pragma unroll
    for (int i = 0; i < 4; ++i) {
        int n = n0 + i;
        valid[i] = (n < N_NODES);
        hrow[i] = (const float4*)(h + (size_t)(valid[i] ? n : (N_NODES - 1)) * IN_DIM);
    }

    float acc[4][4];
    #pragma unroll
    for (int i = 0; i < 4; ++i)
        #pragma unroll
        for (int d = 0; d < 4; ++d) acc[i][d] = 0.f;

    for (int kc = 0; kc < IN_DIM / 4; ++kc) {   // 32 iters, 4 k each
        float4 hv[4];
        #pragma unroll
        for (int i = 0; i < 4; ++i) hv[i] = hrow[i][kc];
        #pragma unroll
        for (int j = 0; j < 4; ++j) {
            float4 wv = *(const float4*)(Wlds + (size_t)(kc * 4 + j) * OUT_DIM + og * 4);
            #pragma unroll
            for (int i = 0; i < 4; ++i) {
                float hh = (j == 0) ? hv[i].x : (j == 1) ? hv[i].y : (j == 2) ? hv[i].z : hv[i].w;
                acc[i][0] += hh * wv.x;
                acc[i][1] += hh * wv.y;
                acc[i][2] += hh * wv.z;
                acc[i][3] += hh * wv.w;
            }
        }
    }

    #pragma unroll
    for (int i = 0; i < 4; ++i) {
        if (!valid[i]) continue;
        uint* zr = z16 + (size_t)(n0 + i) * (OUT_DIM / 2) + og * 2;
        zr[0] = f2h(acc[i][0]) | (f2h(acc[i][1]) << 16);
        zr[1] = f2h(acc[i][2]) | (f2h(acc[i][3]) << 16);
    }

    float was0 = W_attn[og * 4], was1 = W_attn[og * 4 + 1],
          was2 = W_attn[og * 4 + 2], was3 = W_attn[og * 4 + 3];
    float wad0 = W_attn[64 + og * 4], wad1 = W_attn[64 + og * 4 + 1],
          wad2 = W_attn[64 + og * 4 + 2], wad3 = W_attn[64 + og * 4 + 3];
    #pragma unroll
    for (int i = 0; i < 4; ++i) {
        float ps = acc[i][0] * was0 + acc[i][1] * was1 + acc[i][2] * was2 + acc[i][3] * was3;
        float pd = acc[i][0] * wad0 + acc[i][1] * wad1 + acc[i][2] * wad2 + acc[i][3] * wad3;
        ps += __shfl_xor(ps, 1, 64); ps += __shfl_xor(ps, 2, 64);
        ps += __shfl_xor(ps, 4, 64); ps += __shfl_xor(ps, 8, 64);
        pd += __shfl_xor(pd, 1, 64); pd += __shfl_xor(pd, 2, 64);
        pd += __shfl_xor(pd, 4, 64); pd += __shfl_xor(pd, 8, 64);
        if (og == 0 && valid[i]) { a_src[n0 + i] = ps; a_dst[n0 + i] = pd; }
    }
}

// K2: binned scatter, register-held entries (no LDS staging). Each thread owns
// 4 consecutive edges (int4/float4 loads). Payload = a_src[s] + c*embed (f32;
// leaky+exp deferred to gather). Key in regs: src:16 | dl:6 | bucket:10.
// Pass 1: compute + LDS histogram by bucket. Reserve dense ranges (1 atomic
// per nonempty bucket). Pass 2: write from registers to dense positions
// (line-dense writes).
__launch_bounds__(1024)
__global__ void k_binscat(const int* __restrict__ src, const int* __restrict__ dst,
                          const float* __restrict__ embed,
                          const float* __restrict__ a_src,
                          const float* __restrict__ c_ws,
                          int* __restrict__ gcursor, uint2* __restrict__ entries) {
    __shared__ int hist[NBUCK];
    __shared__ int boff[NBUCK];
    int t = threadIdx.x;
    if (t < NBUCK) hist[t] = 0;
    __syncthreads();

    int e0 = blockIdx.x * EPB;
    int e1 = e0 + EPB; if (e1 > N_EDGES) e1 = N_EDGES;
    int m = e1 - e0;
    float cc = c_ws[0];

    uint keyr[4]; float valr[4];
    bool own[4] = {false, false, false, false};

    int i0 = t * 4;
    if (i0 + 3 < m) {
        int4   s4 = ((const int4*)(src + e0))[t];
        int4   d4 = ((const int4*)(dst + e0))[t];
        float4 m4 = ((const float4*)(embed + e0))[t];
        int    ss[4] = {s4.x, s4.y, s4.z, s4.w};
        int    dd[4] = {d4.x, d4.y, d4.z, d4.w};
        float  mm[4] = {m4.x, m4.y, m4.z, m4.w};
        #pragma unroll
        for (int u = 0; u < 4; ++u) {
            uint b = (uint)dd[u] >> BUCK_SHIFT, dl = (uint)dd[u] & (BUCK_NODES - 1);
            keyr[u] = (uint)ss[u] | (dl << 16) | (b << 22);
            valr[u] = a_src[ss[u]] + cc * mm[u];
            own[u] = true;
            atomicAdd(&hist[b], 1);
        }
    } else {
        #pragma unroll
        for (int u = 0; u < 4; ++u) {
            int i = i0 + u;
            if (i < m) {
                int e = e0 + i;
                int s = src[e], d = dst[e];
                uint b = (uint)d >> BUCK_SHIFT, dl = (uint)d & (BUCK_NODES - 1);
                keyr[u] = (uint)s | (dl << 16) | (b << 22);
                valr[u] = a_src[s] + cc * embed[e];
                own[u] = true;
                atomicAdd(&hist[b], 1);
            }
        }
    }
    __syncthreads();

    // reserve dense global ranges; reset hist as running cursor
    if (t < NBUCK) {
        int c = hist[t];
        boff[t] = c ? atomicAdd(&gcursor[t], c) : 0;
        hist[t] = 0;
    }
    __syncthreads();

    // pass 2: registers -> dense global write
    #pragma unroll
    for (int u = 0; u < 4; ++u) {
        if (!own[u]) continue;
        uint b = keyr[u] >> 22;
        int pos = boff[b] + atomicAdd(&hist[b], 1);
        entries[pos] = make_uint2(keyr[u] & 0x3FFFFFu, __float_as_uint(valr[u]));
    }
}

// K3: one block (1024 threads, 16 waves) per 64-node bucket; 19.5KB LDS ->
// thread-limited 2 blocks/CU = 32 waves/CU; 782 blocks ≈ 3/CU (balanced).
// a_dst for the block's 64 nodes in LDS. Phase A: single global read of
// entries -> stash + hist by local dst. Wave 0 scans 64 counters. Phase C:
// ev = partial + a_dst_lds[dl], leaky, exp -> counting-sort into packed 4B
// (src | f16(ex)<<16). Phase D: owner-compute, wave wid handles nodes
// [wid*4, wid*4+4); ceil(c/8) MASKED 8-slot iterations (Poisson(16) degrees:
// 8-slot padding ≈27% of slots vs 46% at 16-slot). Lanes 0-31 edges j..j+3,
// lanes 32-63 edges j+4..j+7; each lane one half2 dim-pair of the f16 z row;
// shfl_xor(32) combine; coalesced float2 out.
__launch_bounds__(1024)
__global__ void k_gather(const int* __restrict__ gcursor, const uint2* __restrict__ entries,
                         const float* __restrict__ a_dst,
                         const uint* __restrict__ z16, float* __restrict__ out) {
    __shared__ uint2 s_stash[CAP];                    // 12 KB
    __shared__ uint  s_pk2[CAP];                      // 6 KB
    __shared__ float s_adst[BUCK_NODES];
    __shared__ int hist[BUCK_NODES], hoff[BUCK_NODES], hcur[BUCK_NODES];

    int b = blockIdx.x;
    int t = threadIdx.x, lane = t & 63, wid = t >> 6;
    int base = b * CAP;
    int m = gcursor[b] - base;      // bucket edge count
    if (m > CAP) m = CAP;           // safety clamp (16-sigma event)

    if (t < BUCK_NODES) {
        hist[t] = 0;
        int n = b * BUCK_NODES + t;
        s_adst[t] = (n < N_NODES) ? a_dst[n] : 0.f;
    }
    __syncthreads();

    // phase A: single global read -> stash + histogram
    for (int i = t; i < m; i += 1024) {
        uint2 p = entries[base + i];
        s_stash[i] = p;
        atomicAdd(&hist[(p.x >> 16) & 63], 1);
    }
    __syncthreads();

    if (wid == 0) {  // wave 0: exclusive scan of 64 counters
        int v = hist[lane], sc = v;
        #pragma unroll
        for (int off = 1; off < 64; off <<= 1) {
            int u = __shfl_up(sc, off, 64);
            if (lane >= off) sc += u;
        }
        hoff[lane] = sc - v;
        hcur[lane] = sc - v;
    }
    __syncthreads();

    // phase C: finish e (leaky+exp) and counting-sort into packed 4B
    for (int i = t; i < m; i += 1024) {
        uint2 p = s_stash[i];
        int dl = (p.x >> 16) & 63;
        float ev = __uint_as_float(p.y) + s_adst[dl];
        ev = (ev >= 0.f) ? ev : NEG_SLOPE * ev;
        float ex = __expf(ev);  // segment-max skipped: softmax shift-invariant, e is O(5)
        int pos = atomicAdd(&hcur[dl], 1);
        s_pk2[pos] = (p.x & 0xFFFFu) | (f2h(ex) << 16);
    }
    __syncthreads();

    // phase D: owner-compute with masked 8-slot iterations
    int half = lane >> 5, dp = lane & 31;
    for (int k = 0; k < 4; ++k) {
        int dl = wid * 4 + k;
        int n = b * BUCK_NODES + dl;
        if (n >= N_NODES) continue;
        int j0 = hoff[dl], c = hist[dl], j1 = j0 + c;
        float accx = 0.f, accy = 0.f, den = 0.f;
        for (int j = j0; j < j1; j += 8) {
            uint pk[4];
            #pragma unroll
            for (int u = 0; u < 4; ++u) {
                int idx = j + 4 * half + u;
                int idc = (idx < j1) ? idx : (j1 - 1);
                pk[u] = s_pk2[idc];
                if (idx >= j1) pk[u] &= 0xFFFFu;   // zero f16 ex -> no-op edge
            }
            uint zv[4];
            #pragma unroll
            for (int u = 0; u < 4; ++u) zv[u] = z16[(size_t)(pk[u] & 0xFFFFu) * 32 + dp];
            #pragma unroll
            for (int u = 0; u < 4; ++u) {
                float ex = h2f((unsigned short)(pk[u] >> 16));
                den  += ex;
                accx += ex * h2f((unsigned short)(zv[u] & 0xFFFFu));
                accy += ex * h2f((unsigned short)(zv[u] >> 16));
            }
        }
        accx += __shfl_xor(accx, 32, 64);
        accy += __shfl_xor(accy, 32, 64);
        den  += __shfl_xor(den, 32, 64);
        if (lane < 32) {
            float2 r = (c > 0) ? make_float2(accx / den, accy / den) : make_float2(0.f, 0.f);
            ((float2*)(out + (size_t)n * OUT_DIM))[dp] = r;
        }
    }
}

extern "C" void kernel_launch(void* const* d_in, const int* in_sizes, int n_in,
                              void* d_out, int out_size, void* d_ws, size_t ws_size,
                              hipStream_t stream) {
    const float* h      = (const float*)d_in[0];
    const float* embed  = (const float*)d_in[1];
    const int*   src    = (const int*)d_in[2];
    const int*   dst    = (const int*)d_in[3];
    const float* W_fc   = (const float*)d_in[4];
    const float* W_attn = (const float*)d_in[5];
    const float* W_feat = (const float*)d_in[6];

    float* ws      = (float*)d_ws;
    uint*  z16     = (uint*)ws;                         // N*32 uints (6.4MB)
    uint2* entries = (uint2*)(z16 + (size_t)N_NODES * 32);  // NBUCK*CAP uint2 (9.6MB)
    float* a_src   = (float*)(entries + (size_t)NBUCK * CAP);  // N f32
    float* a_dst   = a_src + N_NODES;                   // N f32
    float* c_ws    = a_dst + N_NODES;                   // 1 f32
    int*   gcursor = (int*)(c_ws + 1);                  // NBUCK int

    float* out = (float*)d_out;

    k_fc<<<(N_NODES * 4 + 255) / 256, 256, 0, stream>>>(h, W_fc, W_attn, W_feat,
                                                        z16, a_src, a_dst, gcursor, c_ws);
    k_binscat<<<NBLK_SCAT, 1024, 0, stream>>>(src, dst, embed, a_src, c_ws,
                                              gcursor, entries);
    k_gather<<<NBUCK, 1024, 0, stream>>>(gcursor, entries, a_dst, z16, out);
}